// Round 1
// baseline (2011.112 us; speedup 1.0000x reference)
//
#include <hip/hip_runtime.h>

#define IN_C  5
#define HID_C 128
#define OUT_C 64

// ---------------------------------------------------------------------------
// Linear-GCN folding: z = A2(A2(X) ) * (W1*W2)  +  rowsum(Ahat)*(b1*W2) + b2
// where Ahat = D^-1/2 (A + I) D^-1/2.  No hidden 128-ch state materialized.
// ---------------------------------------------------------------------------

// deg[i] = 1 (self loop); edges add to it next.
__global__ void k_deg_init(float* deg, int n) {
    int i = blockIdx.x * blockDim.x + threadIdx.x;
    if (i < n) deg[i] = 1.0f;
}

__global__ void k_deg(const int* __restrict__ dst, float* __restrict__ deg, int e) {
    int i = blockIdx.x * blockDim.x + threadIdx.x;
    if (i < e) atomicAdd(&deg[dst[i]], 1.0f);
}

// dis[i] = rsqrt(deg[i]) (in place); t[i] = dis[i] (self-loop term of rowsum);
// agg1[i,:] = x[i,:]*dis[i]^2 (self-loop term of Ahat*X).
__global__ void k_dis(const float* __restrict__ x, float* __restrict__ deg_dis,
                      float* __restrict__ t, float* __restrict__ agg1, int n) {
    int i = blockIdx.x * blockDim.x + threadIdx.x;
    if (i < n) {
        float d = rsqrtf(deg_dis[i]);   // deg >= 1 always (self loop)
        deg_dis[i] = d;
        t[i] = d;
        float dd = d * d;
        #pragma unroll
        for (int k = 0; k < IN_C; ++k)
            agg1[i * IN_C + k] = x[i * IN_C + k] * dd;
    }
}

// Pass 1: agg1[dst] += x[src] * dis[src]*dis[dst];  t[dst] += dis[src]
__global__ void k_pass1(const int* __restrict__ src, const int* __restrict__ dst,
                        const float* __restrict__ dis, const float* __restrict__ x,
                        float* __restrict__ t, float* __restrict__ agg1, int e) {
    int i = blockIdx.x * blockDim.x + threadIdx.x;
    if (i < e) {
        int s = src[i], d = dst[i];
        float ds = dis[s], dd = dis[d];
        float nd = ds * dd;
        atomicAdd(&t[d], ds);
        #pragma unroll
        for (int k = 0; k < IN_C; ++k)
            atomicAdd(&agg1[d * IN_C + k], x[s * IN_C + k] * nd);
    }
}

// agg2 self-loop init: agg2[i,:] = agg1[i,:]*dis[i]^2
__global__ void k_agg2_init(const float* __restrict__ dis, const float* __restrict__ agg1,
                            float* __restrict__ agg2, int n) {
    int i = blockIdx.x * blockDim.x + threadIdx.x;
    if (i < n) {
        float d = dis[i];
        float dd = d * d;
        #pragma unroll
        for (int k = 0; k < IN_C; ++k)
            agg2[i * IN_C + k] = agg1[i * IN_C + k] * dd;
    }
}

// Pass 2: agg2[dst] += agg1[src] * dis[src]*dis[dst]
__global__ void k_pass2(const int* __restrict__ src, const int* __restrict__ dst,
                        const float* __restrict__ dis, const float* __restrict__ agg1,
                        float* __restrict__ agg2, int e) {
    int i = blockIdx.x * blockDim.x + threadIdx.x;
    if (i < e) {
        int s = src[i], d = dst[i];
        float nd = dis[s] * dis[d];
        #pragma unroll
        for (int k = 0; k < IN_C; ++k)
            atomicAdd(&agg2[d * IN_C + k], agg1[s * IN_C + k] * nd);
    }
}

// Fold the weights: Wc = W1 @ W2 (5x64), bc = b1 @ W2 (64). One block, 384 threads.
__global__ void k_fold(const float* __restrict__ W1, const float* __restrict__ b1,
                       const float* __restrict__ W2, float* __restrict__ Wc,
                       float* __restrict__ bc) {
    int j = threadIdx.x;
    if (j < IN_C * OUT_C) {
        int k = j / OUT_C, c = j % OUT_C;
        float acc = 0.0f;
        for (int m = 0; m < HID_C; ++m)
            acc += W1[k * HID_C + m] * W2[m * OUT_C + c];
        Wc[j] = acc;
    } else if (j < IN_C * OUT_C + OUT_C) {
        int c = j - IN_C * OUT_C;
        float acc = 0.0f;
        for (int m = 0; m < HID_C; ++m)
            acc += b1[m] * W2[m * OUT_C + c];
        bc[c] = acc;
    }
}

// out[i,c] = sum_k agg2[i,k]*Wc[k,c] + (dis[i]*t[i])*bc[c] + b2[c]
__global__ void k_out(const float* __restrict__ agg2, const float* __restrict__ dis,
                      const float* __restrict__ t, const float* __restrict__ Wc,
                      const float* __restrict__ bc, const float* __restrict__ b2,
                      float* __restrict__ out, int n) {
    int idx = blockIdx.x * blockDim.x + threadIdx.x;
    int i = idx >> 6;          // OUT_C == 64
    int c = idx & 63;
    if (i < n) {
        float s = dis[i] * t[i];
        float acc = bc[c] * s + b2[c];
        #pragma unroll
        for (int k = 0; k < IN_C; ++k)
            acc += agg2[i * IN_C + k] * Wc[k * OUT_C + c];
        out[idx] = acc;
    }
}

extern "C" void kernel_launch(void* const* d_in, const int* in_sizes, int n_in,
                              void* d_out, int out_size, void* d_ws, size_t ws_size,
                              hipStream_t stream) {
    const float* x   = (const float*)d_in[0];
    const int*   ei  = (const int*)d_in[1];
    const float* W1  = (const float*)d_in[2];
    const float* b1  = (const float*)d_in[3];
    const float* W2  = (const float*)d_in[4];
    const float* b2  = (const float*)d_in[5];
    float* out = (float*)d_out;

    const int n = in_sizes[0] / IN_C;      // 100000
    const int e = in_sizes[1] / 2;         // 3200000
    const int* src = ei;
    const int* dst = ei + e;

    float* ws      = (float*)d_ws;
    float* deg_dis = ws;                   // n  (deg, then dis in place)
    float* t       = ws + n;               // n
    float* agg1    = ws + 2 * n;           // 5n
    float* agg2    = ws + 7 * n;           // 5n
    float* Wc      = ws + 12 * n;          // 320
    float* bc      = Wc + IN_C * OUT_C;    // 64

    const int B = 256;
    const int gN = (n + B - 1) / B;
    const int gE = (e + B - 1) / B;
    const int gO = (n * OUT_C + B - 1) / B;

    k_deg_init<<<gN, B, 0, stream>>>(deg_dis, n);
    k_deg     <<<gE, B, 0, stream>>>(dst, deg_dis, e);
    k_dis     <<<gN, B, 0, stream>>>(x, deg_dis, t, agg1, n);
    k_fold    <<<1, 384, 0, stream>>>(W1, b1, W2, Wc, bc);
    k_pass1   <<<gE, B, 0, stream>>>(src, dst, deg_dis, x, t, agg1, e);
    k_agg2_init<<<gN, B, 0, stream>>>(deg_dis, agg1, agg2, n);
    k_pass2   <<<gE, B, 0, stream>>>(src, dst, deg_dis, agg1, agg2, e);
    k_out     <<<gO, B, 0, stream>>>(agg2, deg_dis, t, Wc, bc, b2, out, n);
}

// Round 2
// 579.856 us; speedup vs baseline: 3.4683x; 3.4683x over previous
//
#include <hip/hip_runtime.h>

#define IN_C  5
#define HID_C 128
#define OUT_C 64

// ---------------------------------------------------------------------------
// Linear-GCN folding + CSR-gather (no float atomics):
//   z = Ahat^2 X (W1 W2) + (Ahat 1)(b1 W2) + b2,  Ahat = D^-1/2 (A+I) D^-1/2
// CSR built per call (histogram + scan + fill-scatter, int atomics only),
// then both Ahat applications are atomic-free gathers over 8-float padded,
// dis-prescaled rows (two aligned float4 loads per edge).
// ---------------------------------------------------------------------------

__global__ void k_zero(int* __restrict__ counts, int n) {
    int i = blockIdx.x * blockDim.x + threadIdx.x;
    if (i < n) counts[i] = 0;
}

__global__ void k_hist(const int* __restrict__ dst, int* __restrict__ counts, int e) {
    int i = blockIdx.x * blockDim.x + threadIdx.x;
    if (i < e) atomicAdd(&counts[dst[i]], 1);
}

// Block-level exclusive scan (1024 threads/block), writes per-block total.
__global__ void k_scanA(const int* __restrict__ counts, int* __restrict__ ptr,
                        int* __restrict__ sums, int n) {
    int gid = blockIdx.x * 1024 + threadIdx.x;
    int lane = threadIdx.x & 63, wave = threadIdx.x >> 6;
    int c = (gid < n) ? counts[gid] : 0;
    int v = c;
    #pragma unroll
    for (int m = 1; m < 64; m <<= 1) {
        int u = __shfl_up(v, m);
        if (lane >= m) v += u;
    }
    __shared__ int wsum[16];
    if (lane == 63) wsum[wave] = v;
    __syncthreads();
    if (wave == 0) {
        int w = (lane < 16) ? wsum[lane] : 0;
        #pragma unroll
        for (int m = 1; m < 16; m <<= 1) {
            int u = __shfl_up(w, m);
            if (lane >= m) w += u;
        }
        if (lane < 16) wsum[lane] = w;
    }
    __syncthreads();
    int base = (wave > 0) ? wsum[wave - 1] : 0;
    int inc = base + v;
    if (gid < n) ptr[gid] = inc - c;                 // exclusive
    if (threadIdx.x == 1023) sums[blockIdx.x] = inc; // block total
}

// Single-block exclusive scan of block sums (nb <= 128).
__global__ void k_scanB(int* __restrict__ sums, int nb) {
    int t = threadIdx.x;
    __shared__ int sh[128];
    int orig = (t < nb) ? sums[t] : 0;
    sh[t] = orig;
    __syncthreads();
    for (int m = 1; m < 128; m <<= 1) {
        int v = (t >= m) ? sh[t - m] : 0;
        __syncthreads();
        sh[t] += v;
        __syncthreads();
    }
    if (t < nb) sums[t] = sh[t] - orig;              // exclusive
}

// Add block offsets; produce final ptr and running-fill copy. counts region
// is reused as fill (counts consumed by k_prep, which runs BEFORE this).
__global__ void k_scanC(int* __restrict__ ptr, const int* __restrict__ sums,
                        int* __restrict__ fill, int n, int e) {
    int i = blockIdx.x * blockDim.x + threadIdx.x;
    if (i < n) {
        int p = ptr[i] + sums[i >> 10];
        ptr[i] = p;
        fill[i] = p;
    }
    if (i == 0) ptr[n] = e;
}

// dis = rsqrt(1+indeg); xs[i*8+k] = x[i,k]*dis (k<5), xs[i*8+5] = dis.
__global__ void k_prep(const float* __restrict__ x, const int* __restrict__ counts,
                       float* __restrict__ dis, float* __restrict__ xs, int n) {
    int i = blockIdx.x * blockDim.x + threadIdx.x;
    if (i < n) {
        float d = rsqrtf(1.0f + (float)counts[i]);
        dis[i] = d;
        float4 q0, q1;
        q0.x = x[i * IN_C + 0] * d;
        q0.y = x[i * IN_C + 1] * d;
        q0.z = x[i * IN_C + 2] * d;
        q0.w = x[i * IN_C + 3] * d;
        q1.x = x[i * IN_C + 4] * d;
        q1.y = d;
        q1.z = 0.0f;
        q1.w = 0.0f;
        ((float4*)(xs + i * 8))[0] = q0;
        ((float4*)(xs + i * 8))[1] = q1;
    }
}

// Bucket src ids by dst (CSR fill). Int atomics only.
__global__ void k_scatter(const int* __restrict__ src, const int* __restrict__ dst,
                          int* __restrict__ fill, int* __restrict__ srclist, int e) {
    int i = blockIdx.x * blockDim.x + threadIdx.x;
    if (i < e) {
        int pos = atomicAdd(&fill[dst[i]], 1);
        srclist[pos] = src[i];
    }
}

// One Ahat application as a gather. 4 threads per node (strided edge split),
// cross-sublane combine via shfl_xor. mode 0: first pass (out = ys, scale
// ch0..4 by dis^2, ch5 (rowsum) by dis). mode 1: second pass (out = agg2,
// scale ch0..4 by dis, pass rowsum through in ch5).
__global__ void k_gather(const int* __restrict__ ptr, const int* __restrict__ srclist,
                         const float* __restrict__ feat, const float* __restrict__ dis,
                         float* __restrict__ out, int n, int mode) {
    int tid = blockIdx.x * blockDim.x + threadIdx.x;
    int node = tid >> 2, sub = tid & 3;
    if (node >= n) return;
    int b = ptr[node], en = ptr[node + 1];
    float4 a0 = {0, 0, 0, 0};
    float ax = 0.0f, ay = 0.0f;
    for (int j = b + sub; j < en; j += 4) {
        int s = srclist[j];
        const float4* p = (const float4*)(feat + s * 8);
        float4 v0 = p[0], v1 = p[1];
        a0.x += v0.x; a0.y += v0.y; a0.z += v0.z; a0.w += v0.w;
        ax += v1.x; ay += v1.y;
    }
    #pragma unroll
    for (int m = 1; m < 4; m <<= 1) {
        a0.x += __shfl_xor(a0.x, m);
        a0.y += __shfl_xor(a0.y, m);
        a0.z += __shfl_xor(a0.z, m);
        a0.w += __shfl_xor(a0.w, m);
        ax   += __shfl_xor(ax, m);
        ay   += __shfl_xor(ay, m);
    }
    if (sub == 0) {
        const float4* ps = (const float4*)(feat + node * 8);
        float4 s0 = ps[0], s1 = ps[1];
        a0.x += s0.x; a0.y += s0.y; a0.z += s0.z; a0.w += s0.w;
        ax += s1.x; ay += s1.y;
        float d = dis[node];
        float4 o0, o1;
        if (mode == 0) {
            float d2 = d * d;
            o0.x = a0.x * d2; o0.y = a0.y * d2; o0.z = a0.z * d2; o0.w = a0.w * d2;
            o1.x = ax * d2;
            o1.y = ay * d;      // rowsum of Ahat
        } else {
            o0.x = a0.x * d; o0.y = a0.y * d; o0.z = a0.z * d; o0.w = a0.w * d;
            o1.x = ax * d;
            o1.y = s1.y;        // rowsum pass-through
        }
        o1.z = 0.0f; o1.w = 0.0f;
        ((float4*)(out + node * 8))[0] = o0;
        ((float4*)(out + node * 8))[1] = o1;
    }
}

// Fold weights: Wc = W1 @ W2 (5x64), bc = b1 @ W2 (64). One block, 384 thr.
__global__ void k_fold(const float* __restrict__ W1, const float* __restrict__ b1,
                       const float* __restrict__ W2, float* __restrict__ Wc,
                       float* __restrict__ bc) {
    int j = threadIdx.x;
    if (j < IN_C * OUT_C) {
        int k = j / OUT_C, c = j % OUT_C;
        float acc = 0.0f;
        for (int m = 0; m < HID_C; ++m)
            acc += W1[k * HID_C + m] * W2[m * OUT_C + c];
        Wc[j] = acc;
    } else if (j < IN_C * OUT_C + OUT_C) {
        int c = j - IN_C * OUT_C;
        float acc = 0.0f;
        for (int m = 0; m < HID_C; ++m)
            acc += b1[m] * W2[m * OUT_C + c];
        bc[c] = acc;
    }
}

// out[i,c] = sum_k agg2[i*8+k]*Wc[k,c] + agg2[i*8+5]*bc[c] + b2[c]
__global__ void k_out(const float* __restrict__ agg2, const float* __restrict__ Wc,
                      const float* __restrict__ bc, const float* __restrict__ b2,
                      float* __restrict__ out, int n) {
    int idx = blockIdx.x * blockDim.x + threadIdx.x;
    int i = idx >> 6, c = idx & 63;
    if (i < n) {
        const float* a = agg2 + i * 8;
        float acc = b2[c] + a[5] * bc[c];
        #pragma unroll
        for (int k = 0; k < IN_C; ++k)
            acc += a[k] * Wc[k * OUT_C + c];
        out[idx] = acc;
    }
}

extern "C" void kernel_launch(void* const* d_in, const int* in_sizes, int n_in,
                              void* d_out, int out_size, void* d_ws, size_t ws_size,
                              hipStream_t stream) {
    const float* x   = (const float*)d_in[0];
    const int*   ei  = (const int*)d_in[1];
    const float* W1  = (const float*)d_in[2];
    const float* b1  = (const float*)d_in[3];
    const float* W2  = (const float*)d_in[4];
    const float* b2  = (const float*)d_in[5];
    float* out = (float*)d_out;

    const int n = in_sizes[0] / IN_C;   // 100000
    const int e = in_sizes[1] / 2;      // 3200000
    const int* src = ei;
    const int* dst = ei + e;

    // Workspace layout (4-byte elements; all offsets multiple of 8 => 32B align)
    int*   srclist = (int*)d_ws;                 // [0, e)
    int*   counts  = srclist + e;                // n    (reused as fill)
    int*   ptr     = counts + n;                 // n+8
    int*   sums    = ptr + n + 8;                // 128
    float* dis     = (float*)(sums + 128);       // n
    float* xs      = dis + n;                    // 8n  (reused as agg2)
    float* ys      = xs + 8 * n;                 // 8n
    float* Wc      = ys + 8 * n;                 // 320
    float* bc      = Wc + IN_C * OUT_C;          // 64
    float* agg2    = xs;                         // alias (xs dead after gather1)

    const int B = 256;
    const int gN  = (n + B - 1) / B;
    const int gE  = (e + B - 1) / B;
    const int gG  = (4 * n + B - 1) / B;         // 4 threads/node
    const int gO  = (n * OUT_C + B - 1) / B;
    const int nbS = (n + 1023) / 1024;           // scan blocks (98)

    k_zero   <<<gN, B, 0, stream>>>(counts, n);
    k_hist   <<<gE, B, 0, stream>>>(dst, counts, e);
    k_scanA  <<<nbS, 1024, 0, stream>>>(counts, ptr, sums, n);
    k_scanB  <<<1, 128, 0, stream>>>(sums, nbS);
    k_prep   <<<gN, B, 0, stream>>>(x, counts, dis, xs, n);   // consumes counts
    k_fold   <<<1, 384, 0, stream>>>(W1, b1, W2, Wc, bc);
    k_scanC  <<<gN, B, 0, stream>>>(ptr, sums, counts /*fill*/, n, e);
    k_scatter<<<gE, B, 0, stream>>>(src, dst, counts /*fill*/, srclist, e);
    k_gather <<<gG, B, 0, stream>>>(ptr, srclist, xs, dis, ys, n, 0);
    k_gather <<<gG, B, 0, stream>>>(ptr, srclist, ys, dis, agg2, n, 1);
    k_out    <<<gO, B, 0, stream>>>(agg2, Wc, bc, b2, out, n);
}

// Round 3
// 424.996 us; speedup vs baseline: 4.7321x; 1.3644x over previous
//
#include <hip/hip_runtime.h>

#define IN_C  5
#define HID_C 128
#define OUT_C 64

#define KB   256      // nodes per bucket (dst >> 8)
#define NBP  512      // padded bucket count (power of 2 >= NB)
#define TILE 4096     // edges per k_bin block
#define BTH  512      // k_bin / k_agg block size
#define EPT  (TILE / BTH)

// ---------------------------------------------------------------------------
// Linear-GCN folding: z = Ahat^2 X (W1 W2) + (Ahat 1)(b1 W2) + b2.
// Edges radix-partitioned by dst-bucket in LDS (no per-edge global atomics),
// then both Ahat applications are block-per-bucket LDS-accumulated gathers.
// Edge payload packed to 4B: (dst&255)<<24 | src  (requires n < 2^24).
// ---------------------------------------------------------------------------

__global__ void k_zero512(int* __restrict__ gtot) {
    gtot[threadIdx.x] = 0;
}

// Bucket totals via LDS-privatized histogram.
__global__ void k_count(const int* __restrict__ dstp, int* __restrict__ gtot, int e) {
    __shared__ int lh[NBP];
    int tid = threadIdx.x;
    for (int j = tid; j < NBP; j += 256) lh[j] = 0;
    __syncthreads();
    for (int i = blockIdx.x * 256 + tid; i < e; i += gridDim.x * 256)
        atomicAdd(&lh[((unsigned)dstp[i]) >> 8], 1);
    __syncthreads();
    for (int j = tid; j < NBP; j += 256) {
        int v = lh[j];
        if (v) atomicAdd(&gtot[j], v);
    }
}

// Exclusive scan of 512 bucket totals -> gbase (persist) and gcursor (mutable).
__global__ void k_scan(const int* __restrict__ gtot, int* __restrict__ gbase,
                       int* __restrict__ gcursor, int e) {
    __shared__ int sh[NBP];
    int tid = threadIdx.x;              // 512
    int v = gtot[tid];
    sh[tid] = v;
    __syncthreads();
    for (int m = 1; m < NBP; m <<= 1) {
        int u = (tid >= m) ? sh[tid - m] : 0;
        __syncthreads();
        sh[tid] += u;
        __syncthreads();
    }
    int excl = sh[tid] - v;
    gbase[tid] = excl;
    gcursor[tid] = excl;
    if (tid == 0) gbase[NBP] = e;
}

// Radix-partition a 4096-edge tile: LDS counting sort by bucket, one global
// atomic per (tile,bucket) to reserve space, coalesced-run flush.
__global__ __launch_bounds__(BTH) void k_bin(const int* __restrict__ src,
                                             const int* __restrict__ dstp,
                                             int* __restrict__ gcursor,
                                             int* __restrict__ binned, int e) {
    __shared__ int lhist[NBP];
    __shared__ int lbase[NBP];
    __shared__ int lfill[NBP];
    __shared__ int lgpos[NBP];
    __shared__ int sorted[TILE];
    __shared__ unsigned short sbkt[TILE];
    __shared__ int stot;
    int tid = threadIdx.x;
    int tbeg = blockIdx.x * TILE;
    for (int j = tid; j < NBP; j += BTH) { lhist[j] = 0; lfill[j] = 0; }
    __syncthreads();
    int pk[EPT], bk[EPT];
    #pragma unroll
    for (int q = 0; q < EPT; ++q) {
        int idx = tbeg + q * BTH + tid;
        if (idx < e) {
            int s = src[idx], d = dstp[idx];
            pk[q] = ((d & 255) << 24) | s;
            bk[q] = ((unsigned)d) >> 8;
            atomicAdd(&lhist[bk[q]], 1);
        } else bk[q] = -1;
    }
    __syncthreads();
    // Hillis-Steele inclusive scan of lhist in lbase
    int hv = lhist[tid];
    lbase[tid] = hv;
    __syncthreads();
    for (int m = 1; m < NBP; m <<= 1) {
        int u = (tid >= m) ? lbase[tid - m] : 0;
        __syncthreads();
        lbase[tid] += u;
        __syncthreads();
    }
    int incl = lbase[tid];
    lbase[tid] = incl - hv;             // exclusive (own slot only)
    if (tid == NBP - 1) stot = incl;
    if (hv > 0) lgpos[tid] = atomicAdd(&gcursor[tid], hv);
    __syncthreads();
    #pragma unroll
    for (int q = 0; q < EPT; ++q) {
        if (bk[q] >= 0) {
            int slot = lbase[bk[q]] + atomicAdd(&lfill[bk[q]], 1);
            sorted[slot] = pk[q];
            sbkt[slot] = (unsigned short)bk[q];
        }
    }
    __syncthreads();
    int tot = stot;
    for (int slot = tid; slot < tot; slot += BTH) {
        int b = sbkt[slot];
        binned[lgpos[b] + (slot - lbase[b])] = sorted[slot];
    }
}

// Per-bucket in-degree -> dis = rsqrt(1+deg)
__global__ void k_deg(const int* __restrict__ binned, const int* __restrict__ gbase,
                      float* __restrict__ dis, int n) {
    __shared__ int cnt[KB];
    int b = blockIdx.x, tid = threadIdx.x;   // 256
    cnt[tid] = 0;
    __syncthreads();
    int beg = gbase[b], end = gbase[b + 1];
    for (int idx = beg + tid; idx < end; idx += 256)
        atomicAdd(&cnt[((unsigned)binned[idx]) >> 24], 1);
    __syncthreads();
    int i = b * KB + tid;
    if (i < n) dis[i] = rsqrtf(1.0f + (float)cnt[tid]);
}

// xs[i*8+k] = x[i,k]*dis (k<5), xs[i*8+5] = dis, pad 0.
__global__ void k_prep(const float* __restrict__ x, const float* __restrict__ dis,
                       float* __restrict__ xs, int n) {
    int i = blockIdx.x * blockDim.x + threadIdx.x;
    if (i < n) {
        float d = dis[i];
        float4 q0, q1;
        q0.x = x[i * IN_C + 0] * d;
        q0.y = x[i * IN_C + 1] * d;
        q0.z = x[i * IN_C + 2] * d;
        q0.w = x[i * IN_C + 3] * d;
        q1.x = x[i * IN_C + 4] * d;
        q1.y = d;
        q1.z = 0.0f;
        q1.w = 0.0f;
        ((float4*)(xs + i * 8))[0] = q0;
        ((float4*)(xs + i * 8))[1] = q1;
    }
}

// One Ahat application: block-per-bucket, LDS accumulate (ds_add, no return).
// mode 0: feat=xs -> outf=p1 (scale d^2), tout = d*(acc5+d)  (rowsum of Ahat)
// mode 1: feat=p1 -> outf=agg2 (scale d), ch5 ignored.
__global__ __launch_bounds__(BTH) void k_agg(const int* __restrict__ binned,
                                             const int* __restrict__ gbase,
                                             const float* __restrict__ feat,
                                             const float* __restrict__ dis,
                                             float* __restrict__ outf,
                                             float* __restrict__ tout,
                                             int n, int mode) {
    __shared__ float acc[KB * 6];
    int b = blockIdx.x, tid = threadIdx.x;   // 512
    for (int j = tid; j < KB * 6; j += BTH) acc[j] = 0.0f;
    __syncthreads();
    int beg = gbase[b], end = gbase[b + 1];
    for (int idx = beg + tid; idx < end; idx += BTH) {
        int v = binned[idx];
        int s = v & 0xFFFFFF;
        int dl = ((unsigned)v) >> 24;
        const float4* p = (const float4*)(feat + s * 8);
        float4 r0 = p[0], r1 = p[1];
        float* a = acc + dl * 6;
        atomicAdd(a + 0, r0.x);
        atomicAdd(a + 1, r0.y);
        atomicAdd(a + 2, r0.z);
        atomicAdd(a + 3, r0.w);
        atomicAdd(a + 4, r1.x);
        atomicAdd(a + 5, r1.y);
    }
    __syncthreads();
    int i = b * KB + tid;
    if (tid < KB && i < n) {
        float d = dis[i];
        const float4* pr = (const float4*)(feat + i * 8);
        float4 s0 = pr[0], s1 = pr[1];
        float a0 = acc[tid * 6 + 0] + s0.x;
        float a1 = acc[tid * 6 + 1] + s0.y;
        float a2 = acc[tid * 6 + 2] + s0.z;
        float a3 = acc[tid * 6 + 3] + s0.w;
        float a4 = acc[tid * 6 + 4] + s1.x;
        float a5 = acc[tid * 6 + 5] + s1.y;
        float4 o0, o1;
        if (mode == 0) {
            float d2 = d * d;
            o0.x = d2 * a0; o0.y = d2 * a1; o0.z = d2 * a2; o0.w = d2 * a3;
            o1.x = d2 * a4;
            tout[i] = d * a5;
        } else {
            o0.x = d * a0; o0.y = d * a1; o0.z = d * a2; o0.w = d * a3;
            o1.x = d * a4;
        }
        o1.y = 0.0f; o1.z = 0.0f; o1.w = 0.0f;
        ((float4*)(outf + i * 8))[0] = o0;
        ((float4*)(outf + i * 8))[1] = o1;
    }
}

// Fold weights: Wc = W1 @ W2 (5x64), bc = b1 @ W2 (64).
__global__ void k_fold(const float* __restrict__ W1, const float* __restrict__ b1,
                       const float* __restrict__ W2, float* __restrict__ Wc,
                       float* __restrict__ bc) {
    int j = threadIdx.x;
    if (j < IN_C * OUT_C) {
        int k = j / OUT_C, c = j % OUT_C;
        float acc = 0.0f;
        for (int m = 0; m < HID_C; ++m)
            acc += W1[k * HID_C + m] * W2[m * OUT_C + c];
        Wc[j] = acc;
    } else if (j < IN_C * OUT_C + OUT_C) {
        int c = j - IN_C * OUT_C;
        float acc = 0.0f;
        for (int m = 0; m < HID_C; ++m)
            acc += b1[m] * W2[m * OUT_C + c];
        bc[c] = acc;
    }
}

// out[i,c] = sum_k agg2[i*8+k]*Wc[k,c] + t[i]*bc[c] + b2[c]
__global__ void k_out(const float* __restrict__ agg2, const float* __restrict__ t,
                      const float* __restrict__ Wc, const float* __restrict__ bc,
                      const float* __restrict__ b2, float* __restrict__ out, int n) {
    int idx = blockIdx.x * blockDim.x + threadIdx.x;
    int i = idx >> 6, c = idx & 63;
    if (i < n) {
        const float* a = agg2 + i * 8;
        float acc = b2[c] + t[i] * bc[c];
        #pragma unroll
        for (int k = 0; k < IN_C; ++k)
            acc += a[k] * Wc[k * OUT_C + c];
        out[idx] = acc;
    }
}

extern "C" void kernel_launch(void* const* d_in, const int* in_sizes, int n_in,
                              void* d_out, int out_size, void* d_ws, size_t ws_size,
                              hipStream_t stream) {
    const float* x   = (const float*)d_in[0];
    const int*   ei  = (const int*)d_in[1];
    const float* W1  = (const float*)d_in[2];
    const float* b1  = (const float*)d_in[3];
    const float* W2  = (const float*)d_in[4];
    const float* b2  = (const float*)d_in[5];
    float* out = (float*)d_out;

    const int n = in_sizes[0] / IN_C;       // 100000
    const int e = in_sizes[1] / 2;          // 3200000
    const int* src = ei;
    const int* dst = ei + e;
    const int NB = (n + KB - 1) / KB;       // 391
    const int np = (n + 7) & ~7;            // pad for 16B alignment
    const int ep = (e + 7) & ~7;

    // Workspace layout (ints/floats, 4B; offsets multiple of 8 => 32B aligned)
    int*   gtot    = (int*)d_ws;            // 512
    int*   gbase   = gtot + 512;            // 520 (NBP+1 padded)
    int*   gcursor = gbase + 520;           // 512
    int*   binned  = gcursor + 512;         // ep
    float* dis     = (float*)(binned + ep); // np
    float* xs      = dis + np;              // 8*np   (reused as agg2)
    float* p1      = xs + 8 * np;           // 8*np
    float* t       = p1 + 8 * np;           // np
    float* Wc      = t + np;                // 320
    float* bc      = Wc + IN_C * OUT_C;     // 64
    float* agg2    = xs;                    // alias: xs dead after pass 1

    const int gN = (n + 255) / 256;
    const int gO = (n * OUT_C + 255) / 256;
    const int gB = (e + TILE - 1) / TILE;   // 782

    k_zero512<<<1, 512, 0, stream>>>(gtot);
    k_count  <<<512, 256, 0, stream>>>(dst, gtot, e);
    k_scan   <<<1, 512, 0, stream>>>(gtot, gbase, gcursor, e);
    k_bin    <<<gB, BTH, 0, stream>>>(src, dst, gcursor, binned, e);
    k_deg    <<<NB, 256, 0, stream>>>(binned, gbase, dis, n);
    k_prep   <<<gN, 256, 0, stream>>>(x, dis, xs, n);
    k_fold   <<<1, 384, 0, stream>>>(W1, b1, W2, Wc, bc);
    k_agg    <<<NB, BTH, 0, stream>>>(binned, gbase, xs, dis, p1, t, n, 0);
    k_agg    <<<NB, BTH, 0, stream>>>(binned, gbase, p1, dis, agg2, t, n, 1);
    k_out    <<<gO, 256, 0, stream>>>(agg2, t, Wc, bc, b2, out, n);
}

// Round 5
// 397.701 us; speedup vs baseline: 5.0568x; 1.0686x over previous
//
#include <hip/hip_runtime.h>

#define IN_C  5
#define HID_C 128
#define OUT_C 64

#define KB   256      // nodes per bucket (dst >> 8)
#define HB   128      // half-bucket (k_agg/k_deg node span per block)
#define NBP  512      // padded bucket count (power of 2 >= NB)
#define TILE 4096     // edges per k_bin block
#define BTH  512      // k_bin / k_agg block size
#define EPT  (TILE / BTH)

// ---------------------------------------------------------------------------
// Linear-GCN folding: z = Ahat^2 X (W1 W2) + (Ahat 1)(b1 W2) + b2.
// Edges radix-partitioned by dst-bucket in LDS (no per-edge global atomics),
// then both Ahat applications are half-bucket-per-block LDS-accumulated
// gathers with 4-edge manual unroll for memory-level parallelism.
// Edge payload packed to 4B: (dst&255)<<24 | src  (requires n < 2^24).
// NOTE: payload int is NEGATIVE when (dst&255)>=128 — never use sign tests
// for validity (R4 bug); use explicit index-bound flags.
// ---------------------------------------------------------------------------

__global__ void k_zero512(int* __restrict__ gtot) {
    gtot[threadIdx.x] = 0;
}

// Bucket totals via LDS-privatized histogram.
__global__ void k_count(const int* __restrict__ dstp, int* __restrict__ gtot, int e) {
    __shared__ int lh[NBP];
    int tid = threadIdx.x;
    for (int j = tid; j < NBP; j += 256) lh[j] = 0;
    __syncthreads();
    for (int i = blockIdx.x * 256 + tid; i < e; i += gridDim.x * 256)
        atomicAdd(&lh[((unsigned)dstp[i]) >> 8], 1);
    __syncthreads();
    for (int j = tid; j < NBP; j += 256) {
        int v = lh[j];
        if (v) atomicAdd(&gtot[j], v);
    }
}

// Exclusive scan of 512 bucket totals -> gbase (persist) and gcursor.
__global__ void k_scan(const int* __restrict__ gtot, int* __restrict__ gbase,
                       int* __restrict__ gcursor, int e) {
    __shared__ int wtot[8];
    int tid = threadIdx.x;              // 512
    int lane = tid & 63, w = tid >> 6;
    int hv = gtot[tid];
    int v = hv;
    #pragma unroll
    for (int m = 1; m < 64; m <<= 1) { int u = __shfl_up(v, m); if (lane >= m) v += u; }
    if (lane == 63) wtot[w] = v;
    __syncthreads();
    if (w == 0 && lane < 8) {
        int tw = wtot[lane];
        #pragma unroll
        for (int m = 1; m < 8; m <<= 1) { int u = __shfl_up(tw, m); if (lane >= m) tw += u; }
        wtot[lane] = tw;
    }
    __syncthreads();
    int excl = (w ? wtot[w - 1] : 0) + v - hv;
    gbase[tid] = excl;
    gcursor[tid] = excl;
    if (tid == 0) gbase[NBP] = e;
}

// Radix-partition a 4096-edge tile: LDS counting sort by bucket, one global
// atomic per (tile,bucket) to reserve space, coalesced-run flush.
__global__ __launch_bounds__(BTH) void k_bin(const int* __restrict__ src,
                                             const int* __restrict__ dstp,
                                             int* __restrict__ gcursor,
                                             int* __restrict__ binned, int e) {
    __shared__ int lhist[NBP];
    __shared__ int lbase[NBP];
    __shared__ int lfill[NBP];
    __shared__ int lgpos[NBP];
    __shared__ int sorted[TILE];
    __shared__ unsigned short sbkt[TILE];
    __shared__ int wtot[8];
    int tid = threadIdx.x;
    int lane = tid & 63, w = tid >> 6;
    int tbeg = blockIdx.x * TILE;
    for (int j = tid; j < NBP; j += BTH) { lhist[j] = 0; lfill[j] = 0; }
    __syncthreads();
    int pk[EPT], bk[EPT];
    #pragma unroll
    for (int q = 0; q < EPT; ++q) {
        int idx = tbeg + q * BTH + tid;
        if (idx < e) {
            int s = src[idx], d = dstp[idx];
            pk[q] = ((d & 255) << 24) | s;
            bk[q] = ((unsigned)d) >> 8;
            atomicAdd(&lhist[bk[q]], 1);
        } else bk[q] = -1;
    }
    __syncthreads();
    // wave-shuffle scan of lhist (512 entries, 8 waves)
    int hv = lhist[tid];
    int v = hv;
    #pragma unroll
    for (int m = 1; m < 64; m <<= 1) { int u = __shfl_up(v, m); if (lane >= m) v += u; }
    if (lane == 63) wtot[w] = v;
    __syncthreads();
    if (w == 0 && lane < 8) {
        int tw = wtot[lane];
        #pragma unroll
        for (int m = 1; m < 8; m <<= 1) { int u = __shfl_up(tw, m); if (lane >= m) tw += u; }
        wtot[lane] = tw;
    }
    __syncthreads();
    int incl = (w ? wtot[w - 1] : 0) + v;
    lbase[tid] = incl - hv;             // exclusive (own slot only)
    if (hv > 0) lgpos[tid] = atomicAdd(&gcursor[tid], hv);
    __syncthreads();
    #pragma unroll
    for (int q = 0; q < EPT; ++q) {
        if (bk[q] >= 0) {
            int slot = lbase[bk[q]] + atomicAdd(&lfill[bk[q]], 1);
            sorted[slot] = pk[q];
            sbkt[slot] = (unsigned short)bk[q];
        }
    }
    __syncthreads();
    int tot = wtot[7];
    for (int slot = tid; slot < tot; slot += BTH) {
        int b = sbkt[slot];
        binned[lgpos[b] + (slot - lbase[b])] = sorted[slot];
    }
}

// Per-half-bucket in-degree -> dis = rsqrt(1+deg). 4-edge unroll.
// Validity via index-bound flags ONLY (payload sign is meaningful data!).
__global__ __launch_bounds__(256) void k_deg(const int* __restrict__ binned,
                                             const int* __restrict__ gbase,
                                             float* __restrict__ dis, int n) {
    __shared__ int cnt[HB];
    int tid = threadIdx.x;
    int bkt = blockIdx.x >> 1, half = blockIdx.x & 1;
    if (tid < HB) cnt[tid] = 0;
    __syncthreads();
    int beg = gbase[bkt], end = gbase[bkt + 1];
    for (int base = beg + tid; base < end; base += 256 * 4) {
        int i1 = base + 256, i2 = base + 512, i3 = base + 768;
        bool k1 = (i1 < end), k2 = (i2 < end), k3 = (i3 < end);
        int v0 = binned[base];
        int v1 = k1 ? binned[i1] : 0;
        int v2 = k2 ? binned[i2] : 0;
        int v3 = k3 ? binned[i3] : 0;
        unsigned d0 = ((unsigned)v0) >> 24, d1 = ((unsigned)v1) >> 24;
        unsigned d2 = ((unsigned)v2) >> 24, d3 = ((unsigned)v3) >> 24;
        if ((int)(d0 >> 7) == half) atomicAdd(&cnt[d0 & 127], 1);
        if (k1 && (int)(d1 >> 7) == half) atomicAdd(&cnt[d1 & 127], 1);
        if (k2 && (int)(d2 >> 7) == half) atomicAdd(&cnt[d2 & 127], 1);
        if (k3 && (int)(d3 >> 7) == half) atomicAdd(&cnt[d3 & 127], 1);
    }
    __syncthreads();
    if (tid < HB) {
        int node = bkt * KB + half * HB + tid;
        if (node < n) dis[node] = rsqrtf(1.0f + (float)cnt[tid]);
    }
}

// xs[i*8+k] = x[i,k]*dis (k<5), xs[i*8+5] = dis, pad 0.
__global__ void k_prep(const float* __restrict__ x, const float* __restrict__ dis,
                       float* __restrict__ xs, int n) {
    int i = blockIdx.x * blockDim.x + threadIdx.x;
    if (i < n) {
        float d = dis[i];
        float4 q0, q1;
        q0.x = x[i * IN_C + 0] * d;
        q0.y = x[i * IN_C + 1] * d;
        q0.z = x[i * IN_C + 2] * d;
        q0.w = x[i * IN_C + 3] * d;
        q1.x = x[i * IN_C + 4] * d;
        q1.y = d;
        q1.z = 0.0f;
        q1.w = 0.0f;
        ((float4*)(xs + i * 8))[0] = q0;
        ((float4*)(xs + i * 8))[1] = q1;
    }
}

// One Ahat application: half-bucket per block, 4-edge unroll with
// unconditional clamped gathers for MLP, LDS accumulate (stride 7).
// MODE 0: feat=xs -> outf=p1 (scale d^2, ch5 of p1 carries d), tout = d*a5.
// MODE 1: feat=p1 -> outf=agg2 (scale d), no ch5 accumulation.
template<int MODE>
__global__ __launch_bounds__(BTH) void k_agg(const int* __restrict__ binned,
                                             const int* __restrict__ gbase,
                                             const float* __restrict__ feat,
                                             float* __restrict__ outf,
                                             float* __restrict__ tout, int n) {
    __shared__ float acc[HB * 7];
    int tid = threadIdx.x;
    int bkt = blockIdx.x >> 1, half = blockIdx.x & 1;
    for (int j = tid; j < HB * 7; j += BTH) acc[j] = 0.0f;
    __syncthreads();
    int beg = gbase[bkt], end = gbase[bkt + 1];
    for (int base = beg + tid; base < end; base += BTH * 4) {
        int i1 = base + BTH, i2 = base + 2 * BTH, i3 = base + 3 * BTH;
        bool in1 = (i1 < end), in2 = (i2 < end), in3 = (i3 < end);
        int v0 = binned[base];
        int v1 = in1 ? binned[i1] : 0;
        int v2 = in2 ? binned[i2] : 0;
        int v3 = in3 ? binned[i3] : 0;
        unsigned dl0 = ((unsigned)v0) >> 24, dl1 = ((unsigned)v1) >> 24;
        unsigned dl2 = ((unsigned)v2) >> 24, dl3 = ((unsigned)v3) >> 24;
        bool ok0 = ((int)(dl0 >> 7) == half);
        bool ok1 = in1 && ((int)(dl1 >> 7) == half);
        bool ok2 = in2 && ((int)(dl2 >> 7) == half);
        bool ok3 = in3 && ((int)(dl3 >> 7) == half);
        const float4* p0 = (const float4*)(feat + (v0 & 0xFFFFFF) * 8);
        const float4* p1p = (const float4*)(feat + (v1 & 0xFFFFFF) * 8);
        const float4* p2 = (const float4*)(feat + (v2 & 0xFFFFFF) * 8);
        const float4* p3 = (const float4*)(feat + (v3 & 0xFFFFFF) * 8);
        float4 r00 = p0[0],  r01 = p0[1];
        float4 r10 = p1p[0], r11 = p1p[1];
        float4 r20 = p2[0],  r21 = p2[1];
        float4 r30 = p3[0],  r31 = p3[1];
        if (ok0) {
            float* a = acc + (dl0 & 127) * 7;
            atomicAdd(a + 0, r00.x); atomicAdd(a + 1, r00.y);
            atomicAdd(a + 2, r00.z); atomicAdd(a + 3, r00.w);
            atomicAdd(a + 4, r01.x);
            if (MODE == 0) atomicAdd(a + 5, r01.y);
        }
        if (ok1) {
            float* a = acc + (dl1 & 127) * 7;
            atomicAdd(a + 0, r10.x); atomicAdd(a + 1, r10.y);
            atomicAdd(a + 2, r10.z); atomicAdd(a + 3, r10.w);
            atomicAdd(a + 4, r11.x);
            if (MODE == 0) atomicAdd(a + 5, r11.y);
        }
        if (ok2) {
            float* a = acc + (dl2 & 127) * 7;
            atomicAdd(a + 0, r20.x); atomicAdd(a + 1, r20.y);
            atomicAdd(a + 2, r20.z); atomicAdd(a + 3, r20.w);
            atomicAdd(a + 4, r21.x);
            if (MODE == 0) atomicAdd(a + 5, r21.y);
        }
        if (ok3) {
            float* a = acc + (dl3 & 127) * 7;
            atomicAdd(a + 0, r30.x); atomicAdd(a + 1, r30.y);
            atomicAdd(a + 2, r30.z); atomicAdd(a + 3, r30.w);
            atomicAdd(a + 4, r31.x);
            if (MODE == 0) atomicAdd(a + 5, r31.y);
        }
    }
    __syncthreads();
    if (tid < HB) {
        int node = bkt * KB + half * HB + tid;
        if (node < n) {
            const float4* ps = (const float4*)(feat + node * 8);
            float4 s0 = ps[0], s1 = ps[1];
            float d = s1.y;                       // dis carried in ch5
            float a0 = acc[tid * 7 + 0] + s0.x;
            float a1 = acc[tid * 7 + 1] + s0.y;
            float a2 = acc[tid * 7 + 2] + s0.z;
            float a3 = acc[tid * 7 + 3] + s0.w;
            float a4 = acc[tid * 7 + 4] + s1.x;
            float4 o0, o1;
            if (MODE == 0) {
                float a5 = acc[tid * 7 + 5] + s1.y;
                float d2 = d * d;
                o0.x = d2 * a0; o0.y = d2 * a1; o0.z = d2 * a2; o0.w = d2 * a3;
                o1.x = d2 * a4;
                o1.y = d;                          // carry dis into p1
                tout[node] = d * a5;               // rowsum of Ahat
            } else {
                o0.x = d * a0; o0.y = d * a1; o0.z = d * a2; o0.w = d * a3;
                o1.x = d * a4;
                o1.y = 0.0f;
            }
            o1.z = 0.0f; o1.w = 0.0f;
            ((float4*)(outf + node * 8))[0] = o0;
            ((float4*)(outf + node * 8))[1] = o1;
        }
    }
}

// Fold weights: Wc = W1 @ W2 (5x64), bc = b1 @ W2 (64).
__global__ void k_fold(const float* __restrict__ W1, const float* __restrict__ b1,
                       const float* __restrict__ W2, float* __restrict__ Wc,
                       float* __restrict__ bc) {
    int j = threadIdx.x;
    if (j < IN_C * OUT_C) {
        int k = j / OUT_C, c = j % OUT_C;
        float acc = 0.0f;
        for (int m = 0; m < HID_C; ++m)
            acc += W1[k * HID_C + m] * W2[m * OUT_C + c];
        Wc[j] = acc;
    } else if (j < IN_C * OUT_C + OUT_C) {
        int c = j - IN_C * OUT_C;
        float acc = 0.0f;
        for (int m = 0; m < HID_C; ++m)
            acc += b1[m] * W2[m * OUT_C + c];
        bc[c] = acc;
    }
}

// out[i, 4q..4q+3] = sum_k agg2[i*8+k]*Wc[k,:] + t[i]*bc + b2  (float4 lanes)
__global__ void k_out(const float* __restrict__ agg2, const float* __restrict__ t,
                      const float* __restrict__ Wc, const float* __restrict__ bc,
                      const float* __restrict__ b2, float* __restrict__ out, int n) {
    int idx = blockIdx.x * blockDim.x + threadIdx.x;
    int i = idx >> 4, q = idx & 15;
    if (i >= n) return;
    const float* a = agg2 + i * 8;
    float ti = t[i];
    float4 acc = ((const float4*)b2)[q];
    float4 bq  = ((const float4*)bc)[q];
    acc.x += ti * bq.x; acc.y += ti * bq.y; acc.z += ti * bq.z; acc.w += ti * bq.w;
    #pragma unroll
    for (int k = 0; k < IN_C; ++k) {
        float ak = a[k];
        float4 wk = ((const float4*)(Wc + k * OUT_C))[q];
        acc.x += ak * wk.x; acc.y += ak * wk.y; acc.z += ak * wk.z; acc.w += ak * wk.w;
    }
    ((float4*)out)[idx] = acc;
}

extern "C" void kernel_launch(void* const* d_in, const int* in_sizes, int n_in,
                              void* d_out, int out_size, void* d_ws, size_t ws_size,
                              hipStream_t stream) {
    const float* x   = (const float*)d_in[0];
    const int*   ei  = (const int*)d_in[1];
    const float* W1  = (const float*)d_in[2];
    const float* b1  = (const float*)d_in[3];
    const float* W2  = (const float*)d_in[4];
    const float* b2  = (const float*)d_in[5];
    float* out = (float*)d_out;

    const int n = in_sizes[0] / IN_C;       // 100000
    const int e = in_sizes[1] / 2;          // 3200000
    const int* src = ei;
    const int* dst = ei + e;
    const int NB = (n + KB - 1) / KB;       // 391
    const int np = (n + 7) & ~7;
    const int ep = (e + 7) & ~7;

    // Workspace layout (4B elements; offsets multiple of 8 => 32B aligned)
    int*   gtot    = (int*)d_ws;            // 512
    int*   gbase   = gtot + 512;            // 520
    int*   gcursor = gbase + 520;           // 512
    int*   binned  = gcursor + 512;         // ep
    float* dis     = (float*)(binned + ep); // np
    float* xs      = dis + np;              // 8*np  (reused as agg2)
    float* p1      = xs + 8 * np;           // 8*np
    float* t       = p1 + 8 * np;           // np
    float* Wc      = t + np;                // 320
    float* bc      = Wc + IN_C * OUT_C;     // 64
    float* agg2    = xs;                    // alias: xs dead after pass 1

    const int gN = (n + 255) / 256;
    const int gO = (n * 16 + 255) / 256;
    const int gB = (e + TILE - 1) / TILE;   // 782
    const int gA = 2 * NB;                  // 782 half-bucket blocks

    k_zero512<<<1, 512, 0, stream>>>(gtot);
    k_count  <<<512, 256, 0, stream>>>(dst, gtot, e);
    k_scan   <<<1, 512, 0, stream>>>(gtot, gbase, gcursor, e);
    k_bin    <<<gB, BTH, 0, stream>>>(src, dst, gcursor, binned, e);
    k_deg    <<<gA, 256, 0, stream>>>(binned, gbase, dis, n);
    k_prep   <<<gN, 256, 0, stream>>>(x, dis, xs, n);
    k_fold   <<<1, 384, 0, stream>>>(W1, b1, W2, Wc, bc);
    k_agg<0> <<<gA, BTH, 0, stream>>>(binned, gbase, xs, p1, t, n);
    k_agg<1> <<<gA, BTH, 0, stream>>>(binned, gbase, p1, agg2, t, n);
    k_out    <<<gO, 256, 0, stream>>>(agg2, t, Wc, bc, b2, out, n);
}

// Round 6
// 375.766 us; speedup vs baseline: 5.3520x; 1.0584x over previous
//
#include <hip/hip_runtime.h>

#define IN_C  5
#define HID_C 128
#define OUT_C 64

#define KB   256      // nodes per bucket (dst >> 8)
#define NBP  512      // padded bucket count (power of 2 >= NB)
#define TILE 4096     // edges per k_bin block
#define BTH  512      // k_bin / k_aggs block size
#define EPT  (TILE / BTH)
#define S    4        // edge-range slices per bucket (k_aggs / k_degs)

// ---------------------------------------------------------------------------
// Linear-GCN folding: z = Ahat^2 X (W1 W2) + (Ahat 1)(b1 W2) + b2.
// Edges radix-partitioned by dst-bucket in LDS, then each Ahat application
// runs as NB*S edge-range slices: each slice gathers its edges ONCE
// (unconditional accumulate -> compiler can batch loads for MLP), writes a
// 256x6 partial-sum block coalesced; a streaming reduce folds S partials +
// self-loop + dis scaling. Zero global float atomics anywhere.
// Edge payload packed to 4B: (dst&255)<<24 | src  (requires n < 2^24).
// NOTE: payload int is NEGATIVE when (dst&255)>=128 — validity guards must
// use index bounds, never sign tests (R4 bug).
// ---------------------------------------------------------------------------

__global__ void k_zero512(int* __restrict__ gtot) {
    gtot[threadIdx.x] = 0;
}

// Bucket totals via LDS-privatized histogram.
__global__ void k_count(const int* __restrict__ dstp, int* __restrict__ gtot, int e) {
    __shared__ int lh[NBP];
    int tid = threadIdx.x;
    for (int j = tid; j < NBP; j += 256) lh[j] = 0;
    __syncthreads();
    for (int i = blockIdx.x * 256 + tid; i < e; i += gridDim.x * 256)
        atomicAdd(&lh[((unsigned)dstp[i]) >> 8], 1);
    __syncthreads();
    for (int j = tid; j < NBP; j += 256) {
        int v = lh[j];
        if (v) atomicAdd(&gtot[j], v);
    }
}

// Exclusive scan of 512 bucket totals -> gbase (persist) and gcursor.
__global__ void k_scan(const int* __restrict__ gtot, int* __restrict__ gbase,
                       int* __restrict__ gcursor, int e) {
    __shared__ int wtot[8];
    int tid = threadIdx.x;              // 512
    int lane = tid & 63, w = tid >> 6;
    int hv = gtot[tid];
    int v = hv;
    #pragma unroll
    for (int m = 1; m < 64; m <<= 1) { int u = __shfl_up(v, m); if (lane >= m) v += u; }
    if (lane == 63) wtot[w] = v;
    __syncthreads();
    if (w == 0 && lane < 8) {
        int tw = wtot[lane];
        #pragma unroll
        for (int m = 1; m < 8; m <<= 1) { int u = __shfl_up(tw, m); if (lane >= m) tw += u; }
        wtot[lane] = tw;
    }
    __syncthreads();
    int excl = (w ? wtot[w - 1] : 0) + v - hv;
    gbase[tid] = excl;
    gcursor[tid] = excl;
    if (tid == 0) gbase[NBP] = e;
}

// Radix-partition a 4096-edge tile: LDS counting sort by bucket, one global
// atomic per (tile,bucket) to reserve space, coalesced-run flush.
__global__ __launch_bounds__(BTH) void k_bin(const int* __restrict__ src,
                                             const int* __restrict__ dstp,
                                             int* __restrict__ gcursor,
                                             int* __restrict__ binned, int e) {
    __shared__ int lhist[NBP];
    __shared__ int lbase[NBP];
    __shared__ int lfill[NBP];
    __shared__ int lgpos[NBP];
    __shared__ int sorted[TILE];
    __shared__ unsigned short sbkt[TILE];
    __shared__ int wtot[8];
    int tid = threadIdx.x;
    int lane = tid & 63, w = tid >> 6;
    int tbeg = blockIdx.x * TILE;
    for (int j = tid; j < NBP; j += BTH) { lhist[j] = 0; lfill[j] = 0; }
    __syncthreads();
    int pk[EPT], bk[EPT];
    #pragma unroll
    for (int q = 0; q < EPT; ++q) {
        int idx = tbeg + q * BTH + tid;
        if (idx < e) {
            int s = src[idx], d = dstp[idx];
            pk[q] = ((d & 255) << 24) | s;
            bk[q] = ((unsigned)d) >> 8;
            atomicAdd(&lhist[bk[q]], 1);
        } else bk[q] = -1;
    }
    __syncthreads();
    // wave-shuffle scan of lhist (512 entries, 8 waves)
    int hv = lhist[tid];
    int v = hv;
    #pragma unroll
    for (int m = 1; m < 64; m <<= 1) { int u = __shfl_up(v, m); if (lane >= m) v += u; }
    if (lane == 63) wtot[w] = v;
    __syncthreads();
    if (w == 0 && lane < 8) {
        int tw = wtot[lane];
        #pragma unroll
        for (int m = 1; m < 8; m <<= 1) { int u = __shfl_up(tw, m); if (lane >= m) tw += u; }
        wtot[lane] = tw;
    }
    __syncthreads();
    int incl = (w ? wtot[w - 1] : 0) + v;
    lbase[tid] = incl - hv;             // exclusive (own slot only)
    if (hv > 0) lgpos[tid] = atomicAdd(&gcursor[tid], hv);
    __syncthreads();
    #pragma unroll
    for (int q = 0; q < EPT; ++q) {
        if (bk[q] >= 0) {
            int slot = lbase[bk[q]] + atomicAdd(&lfill[bk[q]], 1);
            sorted[slot] = pk[q];
            sbkt[slot] = (unsigned short)bk[q];
        }
    }
    __syncthreads();
    int tot = wtot[7];
    for (int slot = tid; slot < tot; slot += BTH) {
        int b = sbkt[slot];
        binned[lgpos[b] + (slot - lbase[b])] = sorted[slot];
    }
}

// Sliced per-node in-degree: block (bkt, slice) counts its edge range into
// LDS, flushes 256 int partials (summed later in k_prep).
__global__ __launch_bounds__(BTH) void k_degs(const int* __restrict__ binned,
                                              const int* __restrict__ gbase,
                                              int* __restrict__ ipart) {
    __shared__ int cnt[KB];
    int tid = threadIdx.x;
    int bkt = blockIdx.x >> 2, sl = blockIdx.x & 3;
    if (tid < KB) cnt[tid] = 0;
    __syncthreads();
    int beg = gbase[bkt], end = gbase[bkt + 1];
    int slice = (end - beg + S - 1) >> 2;
    int sbeg = beg + sl * slice;
    int send = min(sbeg + slice, end);
    for (int j0 = sbeg + tid * 4; j0 < send; j0 += BTH * 4) {
        bool q1 = (j0 + 1 < send), q2 = (j0 + 2 < send), q3 = (j0 + 3 < send);
        int v0 = binned[j0];
        int v1 = q1 ? binned[j0 + 1] : 0;
        int v2 = q2 ? binned[j0 + 2] : 0;
        int v3 = q3 ? binned[j0 + 3] : 0;
        atomicAdd(&cnt[((unsigned)v0) >> 24], 1);
        if (q1) atomicAdd(&cnt[((unsigned)v1) >> 24], 1);
        if (q2) atomicAdd(&cnt[((unsigned)v2) >> 24], 1);
        if (q3) atomicAdd(&cnt[((unsigned)v3) >> 24], 1);
    }
    __syncthreads();
    if (tid < KB) ipart[blockIdx.x * KB + tid] = cnt[tid];
}

// Sum int partials -> dis; xs[i*8+k] = x[i,k]*dis (k<5), xs[i*8+5] = dis.
__global__ void k_prep(const float* __restrict__ x, const int* __restrict__ ipart,
                       float* __restrict__ xs, int n) {
    int i = blockIdx.x * blockDim.x + threadIdx.x;
    if (i >= n) return;
    int bkt = i >> 8, dl = i & 255;
    const int* ip = ipart + bkt * S * KB + dl;
    int deg = ip[0] + ip[KB] + ip[2 * KB] + ip[3 * KB];
    float d = rsqrtf(1.0f + (float)deg);
    float4 q0, q1;
    q0.x = x[i * IN_C + 0] * d;
    q0.y = x[i * IN_C + 1] * d;
    q0.z = x[i * IN_C + 2] * d;
    q0.w = x[i * IN_C + 3] * d;
    q1.x = x[i * IN_C + 4] * d;
    q1.y = d;
    q1.z = 0.0f;
    q1.w = 0.0f;
    ((float4*)(xs + i * 8))[0] = q0;
    ((float4*)(xs + i * 8))[1] = q1;
}

// One slice of one Ahat application: gather this edge range's features,
// accumulate UNCONDITIONALLY into LDS (all edges belong to this bucket),
// flush 256x6 partial block coalesced. MODE 0 also accumulates ch5 (rowsum).
template<int MODE>
__global__ __launch_bounds__(BTH) void k_aggs(const int* __restrict__ binned,
                                              const int* __restrict__ gbase,
                                              const float* __restrict__ feat,
                                              float* __restrict__ part) {
    __shared__ float acc[KB * 7];      // stride 7: co-prime with 32 banks
    int tid = threadIdx.x;
    int bkt = blockIdx.x >> 2, sl = blockIdx.x & 3;
    for (int j = tid; j < KB * 7; j += BTH) acc[j] = 0.0f;
    __syncthreads();
    int beg = gbase[bkt], end = gbase[bkt + 1];
    int slice = (end - beg + S - 1) >> 2;
    int sbeg = beg + sl * slice;
    int send = min(sbeg + slice, end);
    for (int j0 = sbeg + tid * 4; j0 < send; j0 += BTH * 4) {
        bool q1 = (j0 + 1 < send), q2 = (j0 + 2 < send), q3 = (j0 + 3 < send);
        int v0 = binned[j0];
        int v1 = q1 ? binned[j0 + 1] : v0;
        int v2 = q2 ? binned[j0 + 2] : v0;
        int v3 = q3 ? binned[j0 + 3] : v0;
        const float4* p0 = (const float4*)(feat + (v0 & 0xFFFFFF) * 8);
        const float4* p1 = (const float4*)(feat + (v1 & 0xFFFFFF) * 8);
        const float4* p2 = (const float4*)(feat + (v2 & 0xFFFFFF) * 8);
        const float4* p3 = (const float4*)(feat + (v3 & 0xFFFFFF) * 8);
        float4 r00 = p0[0], r01 = p0[1];
        float4 r10 = p1[0], r11 = p1[1];
        float4 r20 = p2[0], r21 = p2[1];
        float4 r30 = p3[0], r31 = p3[1];
        unsigned dl0 = ((unsigned)v0) >> 24, dl1 = ((unsigned)v1) >> 24;
        unsigned dl2 = ((unsigned)v2) >> 24, dl3 = ((unsigned)v3) >> 24;
        {
            float* a = acc + dl0 * 7;
            atomicAdd(a + 0, r00.x); atomicAdd(a + 1, r00.y);
            atomicAdd(a + 2, r00.z); atomicAdd(a + 3, r00.w);
            atomicAdd(a + 4, r01.x);
            if (MODE == 0) atomicAdd(a + 5, r01.y);
        }
        if (q1) {
            float* a = acc + dl1 * 7;
            atomicAdd(a + 0, r10.x); atomicAdd(a + 1, r10.y);
            atomicAdd(a + 2, r10.z); atomicAdd(a + 3, r10.w);
            atomicAdd(a + 4, r11.x);
            if (MODE == 0) atomicAdd(a + 5, r11.y);
        }
        if (q2) {
            float* a = acc + dl2 * 7;
            atomicAdd(a + 0, r20.x); atomicAdd(a + 1, r20.y);
            atomicAdd(a + 2, r20.z); atomicAdd(a + 3, r20.w);
            atomicAdd(a + 4, r21.x);
            if (MODE == 0) atomicAdd(a + 5, r21.y);
        }
        if (q3) {
            float* a = acc + dl3 * 7;
            atomicAdd(a + 0, r30.x); atomicAdd(a + 1, r30.y);
            atomicAdd(a + 2, r30.z); atomicAdd(a + 3, r30.w);
            atomicAdd(a + 4, r31.x);
            if (MODE == 0) atomicAdd(a + 5, r31.y);
        }
    }
    __syncthreads();
    float* pb = part + (size_t)blockIdx.x * (KB * 6);
    for (int j = tid; j < KB * 6; j += BTH) {
        int row = j / 6, c = j - row * 6;
        pb[j] = acc[row * 7 + c];
    }
}

// Fold S slice-partials + self-loop + dis scaling into the next feature row.
// MODE 0: feat=xs -> outf=p1 (scale d^2; p1 ch5 carries d), tout = d*a5.
// MODE 1: feat=p1 -> outf=agg2 (scale d).
template<int MODE>
__global__ void k_red(const float* __restrict__ part, const float* __restrict__ feat,
                      float* __restrict__ outf, float* __restrict__ tout, int n) {
    int i = blockIdx.x * blockDim.x + threadIdx.x;
    if (i >= n) return;
    int bkt = i >> 8, dl = i & 255;
    const float* pb = part + (size_t)(bkt * S) * (KB * 6) + dl * 6;
    float a0 = 0, a1 = 0, a2 = 0, a3 = 0, a4 = 0, a5 = 0;
    #pragma unroll
    for (int s = 0; s < S; ++s) {
        const float2* q = (const float2*)(pb + s * (KB * 6));  // 8B-aligned
        float2 u0 = q[0], u1 = q[1], u2 = q[2];
        a0 += u0.x; a1 += u0.y; a2 += u1.x; a3 += u1.y; a4 += u2.x; a5 += u2.y;
    }
    const float4* ps = (const float4*)(feat + i * 8);
    float4 s0 = ps[0], s1 = ps[1];
    float d = s1.y;                       // dis carried in ch5
    a0 += s0.x; a1 += s0.y; a2 += s0.z; a3 += s0.w; a4 += s1.x;
    float4 o0, o1;
    if (MODE == 0) {
        a5 += s1.y;
        float d2 = d * d;
        o0.x = d2 * a0; o0.y = d2 * a1; o0.z = d2 * a2; o0.w = d2 * a3;
        o1.x = d2 * a4;
        o1.y = d;                          // carry dis into p1
        tout[i] = d * a5;                  // rowsum of Ahat
    } else {
        o0.x = d * a0; o0.y = d * a1; o0.z = d * a2; o0.w = d * a3;
        o1.x = d * a4;
        o1.y = 0.0f;
    }
    o1.z = 0.0f; o1.w = 0.0f;
    ((float4*)(outf + i * 8))[0] = o0;
    ((float4*)(outf + i * 8))[1] = o1;
}

// Fold weights: Wc = W1 @ W2 (5x64), bc = b1 @ W2 (64).
__global__ void k_fold(const float* __restrict__ W1, const float* __restrict__ b1,
                       const float* __restrict__ W2, float* __restrict__ Wc,
                       float* __restrict__ bc) {
    int j = threadIdx.x;
    if (j < IN_C * OUT_C) {
        int k = j / OUT_C, c = j % OUT_C;
        float acc = 0.0f;
        for (int m = 0; m < HID_C; ++m)
            acc += W1[k * HID_C + m] * W2[m * OUT_C + c];
        Wc[j] = acc;
    } else if (j < IN_C * OUT_C + OUT_C) {
        int c = j - IN_C * OUT_C;
        float acc = 0.0f;
        for (int m = 0; m < HID_C; ++m)
            acc += b1[m] * W2[m * OUT_C + c];
        bc[c] = acc;
    }
}

// out[i, 4q..4q+3] = sum_k agg2[i*8+k]*Wc[k,:] + t[i]*bc + b2  (float4 lanes)
__global__ void k_out(const float* __restrict__ agg2, const float* __restrict__ t,
                      const float* __restrict__ Wc, const float* __restrict__ bc,
                      const float* __restrict__ b2, float* __restrict__ out, int n) {
    int idx = blockIdx.x * blockDim.x + threadIdx.x;
    int i = idx >> 4, q = idx & 15;
    if (i >= n) return;
    const float* a = agg2 + i * 8;
    float ti = t[i];
    float4 acc = ((const float4*)b2)[q];
    float4 bq  = ((const float4*)bc)[q];
    acc.x += ti * bq.x; acc.y += ti * bq.y; acc.z += ti * bq.z; acc.w += ti * bq.w;
    #pragma unroll
    for (int k = 0; k < IN_C; ++k) {
        float ak = a[k];
        float4 wk = ((const float4*)(Wc + k * OUT_C))[q];
        acc.x += ak * wk.x; acc.y += ak * wk.y; acc.z += ak * wk.z; acc.w += ak * wk.w;
    }
    ((float4*)out)[idx] = acc;
}

extern "C" void kernel_launch(void* const* d_in, const int* in_sizes, int n_in,
                              void* d_out, int out_size, void* d_ws, size_t ws_size,
                              hipStream_t stream) {
    const float* x   = (const float*)d_in[0];
    const int*   ei  = (const int*)d_in[1];
    const float* W1  = (const float*)d_in[2];
    const float* b1  = (const float*)d_in[3];
    const float* W2  = (const float*)d_in[4];
    const float* b2  = (const float*)d_in[5];
    float* out = (float*)d_out;

    const int n = in_sizes[0] / IN_C;       // 100000
    const int e = in_sizes[1] / 2;          // 3200000
    const int* src = ei;
    const int* dst = ei + e;
    const int NB = (n + KB - 1) / KB;       // 391
    const int np = (n + 7) & ~7;
    const int ep = (e + 7) & ~7;
    const int NS = NB * S;                  // 1564 slice blocks

    // Workspace layout (4B elements; every segment size multiple of 8)
    int*   gtot    = (int*)d_ws;            // 512
    int*   gbase   = gtot + 512;            // 520
    int*   gcursor = gbase + 520;           // 512 + pad 8 -> 1552 total
    int*   binned  = (int*)d_ws + 1552;     // ep
    int*   ipart   = binned + ep;           // NS*KB      (1564*256)
    float* part    = (float*)(ipart + NS * KB);  // NS*KB*6 (9.6 MB)
    float* xs      = part + (size_t)NS * KB * 6; // 8*np   (reused as agg2)
    float* p1      = xs + 8 * np;           // 8*np
    float* t       = p1 + 8 * np;           // np
    float* Wc      = t + np;                // 320
    float* bc      = Wc + IN_C * OUT_C;     // 64
    float* agg2    = xs;                    // alias: xs dead after pass 1

    const int gN = (n + 255) / 256;
    const int gO = (n * 16 + 255) / 256;
    const int gB = (e + TILE - 1) / TILE;   // 782

    k_zero512<<<1, 512, 0, stream>>>(gtot);
    k_count  <<<512, 256, 0, stream>>>(dst, gtot, e);
    k_scan   <<<1, 512, 0, stream>>>(gtot, gbase, gcursor, e);
    k_bin    <<<gB, BTH, 0, stream>>>(src, dst, gcursor, binned, e);
    k_degs   <<<NS, BTH, 0, stream>>>(binned, gbase, ipart);
    k_prep   <<<gN, 256, 0, stream>>>(x, ipart, xs, n);
    k_fold   <<<1, 384, 0, stream>>>(W1, b1, W2, Wc, bc);
    k_aggs<0><<<NS, BTH, 0, stream>>>(binned, gbase, xs, part);
    k_red<0> <<<gN, 256, 0, stream>>>(part, xs, p1, t, n);
    k_aggs<1><<<NS, BTH, 0, stream>>>(binned, gbase, p1, part);
    k_red<1> <<<gN, 256, 0, stream>>>(part, p1, agg2, t, n);
    k_out    <<<gO, 256, 0, stream>>>(agg2, t, Wc, bc, b2, out, n);
}

// Round 7
// 375.402 us; speedup vs baseline: 5.3572x; 1.0010x over previous
//
#include <hip/hip_runtime.h>

#define IN_C  5
#define HID_C 128
#define OUT_C 64

#define KB   256      // nodes per bucket (dst >> 8)
#define NBP  512      // padded bucket count (power of 2 >= NB)
#define TILE 4096     // edges per k_bin block
#define BTH  512      // k_bin / k_aggs block size
#define EPT  (TILE / BTH)
#define S    4        // edge-range slices per bucket (k_aggs / k_degs)

// ---------------------------------------------------------------------------
// Linear-GCN folding: z = Ahat^2 X (W1 W2) + (Ahat 1)(b1 W2) + b2.
// Edges radix-partitioned by dst-bucket in LDS, then each Ahat application
// runs as NB*S edge-range slices gathering features once, accumulating into
// LDS via HARDWARE float atomics (unsafeAtomicAdd -> ds_add_f32, no CAS
// loop; plain atomicAdd(float*) compiles to a serial CAS retry loop = R6's
// 40x idle-time bug), flushing 256x6 partials; k_red folds S partials +
// self-loop + dis scaling. Edge payload packed 4B: (dst&255)<<24 | src.
// NOTE: payload int is NEGATIVE when (dst&255)>=128 — validity guards must
// use index bounds, never sign tests (R4 bug).
// ---------------------------------------------------------------------------

__device__ __forceinline__ void lds_fadd(float* p, float v) {
    unsafeAtomicAdd(p, v);   // hardware ds_add_f32 (fire-and-forget)
}

__global__ void k_zero512(int* __restrict__ gtot) {
    gtot[threadIdx.x] = 0;
}

// Bucket totals via LDS-privatized histogram (int atomics are native HW).
__global__ void k_count(const int* __restrict__ dstp, int* __restrict__ gtot, int e) {
    __shared__ int lh[NBP];
    int tid = threadIdx.x;
    for (int j = tid; j < NBP; j += 256) lh[j] = 0;
    __syncthreads();
    for (int i = blockIdx.x * 256 + tid; i < e; i += gridDim.x * 256)
        atomicAdd(&lh[((unsigned)dstp[i]) >> 8], 1);
    __syncthreads();
    for (int j = tid; j < NBP; j += 256) {
        int v = lh[j];
        if (v) atomicAdd(&gtot[j], v);
    }
}

// Exclusive scan of 512 bucket totals -> gbase (persist) and gcursor.
__global__ void k_scan(const int* __restrict__ gtot, int* __restrict__ gbase,
                       int* __restrict__ gcursor, int e) {
    __shared__ int wtot[8];
    int tid = threadIdx.x;              // 512
    int lane = tid & 63, w = tid >> 6;
    int hv = gtot[tid];
    int v = hv;
    #pragma unroll
    for (int m = 1; m < 64; m <<= 1) { int u = __shfl_up(v, m); if (lane >= m) v += u; }
    if (lane == 63) wtot[w] = v;
    __syncthreads();
    if (w == 0 && lane < 8) {
        int tw = wtot[lane];
        #pragma unroll
        for (int m = 1; m < 8; m <<= 1) { int u = __shfl_up(tw, m); if (lane >= m) tw += u; }
        wtot[lane] = tw;
    }
    __syncthreads();
    int excl = (w ? wtot[w - 1] : 0) + v - hv;
    gbase[tid] = excl;
    gcursor[tid] = excl;
    if (tid == 0) gbase[NBP] = e;
}

// Radix-partition a 4096-edge tile: LDS counting sort by bucket, one global
// atomic per (tile,bucket) to reserve space, coalesced-run flush.
__global__ __launch_bounds__(BTH) void k_bin(const int* __restrict__ src,
                                             const int* __restrict__ dstp,
                                             int* __restrict__ gcursor,
                                             int* __restrict__ binned, int e) {
    __shared__ int lhist[NBP];
    __shared__ int lbase[NBP];
    __shared__ int lfill[NBP];
    __shared__ int lgpos[NBP];
    __shared__ int sorted[TILE];
    __shared__ unsigned short sbkt[TILE];
    __shared__ int wtot[8];
    int tid = threadIdx.x;
    int lane = tid & 63, w = tid >> 6;
    int tbeg = blockIdx.x * TILE;
    for (int j = tid; j < NBP; j += BTH) { lhist[j] = 0; lfill[j] = 0; }
    __syncthreads();
    int pk[EPT], bk[EPT];
    #pragma unroll
    for (int q = 0; q < EPT; ++q) {
        int idx = tbeg + q * BTH + tid;
        if (idx < e) {
            int s = src[idx], d = dstp[idx];
            pk[q] = ((d & 255) << 24) | s;
            bk[q] = ((unsigned)d) >> 8;
            atomicAdd(&lhist[bk[q]], 1);
        } else bk[q] = -1;
    }
    __syncthreads();
    // wave-shuffle scan of lhist (512 entries, 8 waves)
    int hv = lhist[tid];
    int v = hv;
    #pragma unroll
    for (int m = 1; m < 64; m <<= 1) { int u = __shfl_up(v, m); if (lane >= m) v += u; }
    if (lane == 63) wtot[w] = v;
    __syncthreads();
    if (w == 0 && lane < 8) {
        int tw = wtot[lane];
        #pragma unroll
        for (int m = 1; m < 8; m <<= 1) { int u = __shfl_up(tw, m); if (lane >= m) tw += u; }
        wtot[lane] = tw;
    }
    __syncthreads();
    int incl = (w ? wtot[w - 1] : 0) + v;
    lbase[tid] = incl - hv;             // exclusive (own slot only)
    if (hv > 0) lgpos[tid] = atomicAdd(&gcursor[tid], hv);
    __syncthreads();
    #pragma unroll
    for (int q = 0; q < EPT; ++q) {
        if (bk[q] >= 0) {
            int slot = lbase[bk[q]] + atomicAdd(&lfill[bk[q]], 1);
            sorted[slot] = pk[q];
            sbkt[slot] = (unsigned short)bk[q];
        }
    }
    __syncthreads();
    int tot = wtot[7];
    for (int slot = tid; slot < tot; slot += BTH) {
        int b = sbkt[slot];
        binned[lgpos[b] + (slot - lbase[b])] = sorted[slot];
    }
}

// Sliced per-node in-degree: block (bkt, slice) counts its edge range into
// LDS, flushes 256 int partials (summed later in k_prep).
__global__ __launch_bounds__(BTH) void k_degs(const int* __restrict__ binned,
                                              const int* __restrict__ gbase,
                                              int* __restrict__ ipart) {
    __shared__ int cnt[KB];
    int tid = threadIdx.x;
    int bkt = blockIdx.x >> 2, sl = blockIdx.x & 3;
    if (tid < KB) cnt[tid] = 0;
    __syncthreads();
    int beg = gbase[bkt], end = gbase[bkt + 1];
    int slice = (end - beg + S - 1) >> 2;
    int sbeg = beg + sl * slice;
    int send = min(sbeg + slice, end);
    for (int j0 = sbeg + tid * 4; j0 < send; j0 += BTH * 4) {
        bool q1 = (j0 + 1 < send), q2 = (j0 + 2 < send), q3 = (j0 + 3 < send);
        int v0 = binned[j0];
        int v1 = q1 ? binned[j0 + 1] : 0;
        int v2 = q2 ? binned[j0 + 2] : 0;
        int v3 = q3 ? binned[j0 + 3] : 0;
        atomicAdd(&cnt[((unsigned)v0) >> 24], 1);
        if (q1) atomicAdd(&cnt[((unsigned)v1) >> 24], 1);
        if (q2) atomicAdd(&cnt[((unsigned)v2) >> 24], 1);
        if (q3) atomicAdd(&cnt[((unsigned)v3) >> 24], 1);
    }
    __syncthreads();
    if (tid < KB) ipart[blockIdx.x * KB + tid] = cnt[tid];
}

// Sum int partials -> dis; xs[i*8+k] = x[i,k]*dis (k<5), xs[i*8+5] = dis.
__global__ void k_prep(const float* __restrict__ x, const int* __restrict__ ipart,
                       float* __restrict__ xs, int n) {
    int i = blockIdx.x * blockDim.x + threadIdx.x;
    if (i >= n) return;
    int bkt = i >> 8, dl = i & 255;
    const int* ip = ipart + bkt * S * KB + dl;
    int deg = ip[0] + ip[KB] + ip[2 * KB] + ip[3 * KB];
    float d = rsqrtf(1.0f + (float)deg);
    float4 q0, q1;
    q0.x = x[i * IN_C + 0] * d;
    q0.y = x[i * IN_C + 1] * d;
    q0.z = x[i * IN_C + 2] * d;
    q0.w = x[i * IN_C + 3] * d;
    q1.x = x[i * IN_C + 4] * d;
    q1.y = d;
    q1.z = 0.0f;
    q1.w = 0.0f;
    ((float4*)(xs + i * 8))[0] = q0;
    ((float4*)(xs + i * 8))[1] = q1;
}

// One slice of one Ahat application: gather this edge range's features,
// accumulate into LDS via HW ds_add_f32, flush 256x6 partial block.
// MODE 0 also accumulates ch5 (rowsum of Ahat).
template<int MODE>
__global__ __launch_bounds__(BTH) void k_aggs(const int* __restrict__ binned,
                                              const int* __restrict__ gbase,
                                              const float* __restrict__ feat,
                                              float* __restrict__ part) {
    __shared__ float acc[KB * 7];      // stride 7: co-prime with 32 banks
    int tid = threadIdx.x;
    int bkt = blockIdx.x >> 2, sl = blockIdx.x & 3;
    for (int j = tid; j < KB * 7; j += BTH) acc[j] = 0.0f;
    __syncthreads();
    int beg = gbase[bkt], end = gbase[bkt + 1];
    int slice = (end - beg + S - 1) >> 2;
    int sbeg = beg + sl * slice;
    int send = min(sbeg + slice, end);
    for (int j0 = sbeg + tid * 4; j0 < send; j0 += BTH * 4) {
        bool q1 = (j0 + 1 < send), q2 = (j0 + 2 < send), q3 = (j0 + 3 < send);
        int v0 = binned[j0];
        int v1 = q1 ? binned[j0 + 1] : v0;
        int v2 = q2 ? binned[j0 + 2] : v0;
        int v3 = q3 ? binned[j0 + 3] : v0;
        const float4* p0 = (const float4*)(feat + (v0 & 0xFFFFFF) * 8);
        const float4* p1 = (const float4*)(feat + (v1 & 0xFFFFFF) * 8);
        const float4* p2 = (const float4*)(feat + (v2 & 0xFFFFFF) * 8);
        const float4* p3 = (const float4*)(feat + (v3 & 0xFFFFFF) * 8);
        float4 r00 = p0[0], r01 = p0[1];
        float4 r10 = p1[0], r11 = p1[1];
        float4 r20 = p2[0], r21 = p2[1];
        float4 r30 = p3[0], r31 = p3[1];
        unsigned dl0 = ((unsigned)v0) >> 24, dl1 = ((unsigned)v1) >> 24;
        unsigned dl2 = ((unsigned)v2) >> 24, dl3 = ((unsigned)v3) >> 24;
        {
            float* a = acc + dl0 * 7;
            lds_fadd(a + 0, r00.x); lds_fadd(a + 1, r00.y);
            lds_fadd(a + 2, r00.z); lds_fadd(a + 3, r00.w);
            lds_fadd(a + 4, r01.x);
            if (MODE == 0) lds_fadd(a + 5, r01.y);
        }
        if (q1) {
            float* a = acc + dl1 * 7;
            lds_fadd(a + 0, r10.x); lds_fadd(a + 1, r10.y);
            lds_fadd(a + 2, r10.z); lds_fadd(a + 3, r10.w);
            lds_fadd(a + 4, r11.x);
            if (MODE == 0) lds_fadd(a + 5, r11.y);
        }
        if (q2) {
            float* a = acc + dl2 * 7;
            lds_fadd(a + 0, r20.x); lds_fadd(a + 1, r20.y);
            lds_fadd(a + 2, r20.z); lds_fadd(a + 3, r20.w);
            lds_fadd(a + 4, r21.x);
            if (MODE == 0) lds_fadd(a + 5, r21.y);
        }
        if (q3) {
            float* a = acc + dl3 * 7;
            lds_fadd(a + 0, r30.x); lds_fadd(a + 1, r30.y);
            lds_fadd(a + 2, r30.z); lds_fadd(a + 3, r30.w);
            lds_fadd(a + 4, r31.x);
            if (MODE == 0) lds_fadd(a + 5, r31.y);
        }
    }
    __syncthreads();
    float* pb = part + (size_t)blockIdx.x * (KB * 6);
    for (int j = tid; j < KB * 6; j += BTH) {
        int row = j / 6, c = j - row * 6;
        pb[j] = acc[row * 7 + c];
    }
}

// Fold S slice-partials + self-loop + dis scaling into the next feature row.
// MODE 0: feat=xs -> outf=p1 (scale d^2; p1 ch5 carries d), tout = d*a5.
// MODE 1: feat=p1 -> outf=agg2 (scale d).
template<int MODE>
__global__ void k_red(const float* __restrict__ part, const float* __restrict__ feat,
                      float* __restrict__ outf, float* __restrict__ tout, int n) {
    int i = blockIdx.x * blockDim.x + threadIdx.x;
    if (i >= n) return;
    int bkt = i >> 8, dl = i & 255;
    const float* pb = part + (size_t)(bkt * S) * (KB * 6) + dl * 6;
    float a0 = 0, a1 = 0, a2 = 0, a3 = 0, a4 = 0, a5 = 0;
    #pragma unroll
    for (int s = 0; s < S; ++s) {
        const float2* q = (const float2*)(pb + s * (KB * 6));  // 8B-aligned
        float2 u0 = q[0], u1 = q[1], u2 = q[2];
        a0 += u0.x; a1 += u0.y; a2 += u1.x; a3 += u1.y; a4 += u2.x; a5 += u2.y;
    }
    const float4* ps = (const float4*)(feat + i * 8);
    float4 s0 = ps[0], s1 = ps[1];
    float d = s1.y;                       // dis carried in ch5
    a0 += s0.x; a1 += s0.y; a2 += s0.z; a3 += s0.w; a4 += s1.x;
    float4 o0, o1;
    if (MODE == 0) {
        a5 += s1.y;
        float d2 = d * d;
        o0.x = d2 * a0; o0.y = d2 * a1; o0.z = d2 * a2; o0.w = d2 * a3;
        o1.x = d2 * a4;
        o1.y = d;                          // carry dis into p1
        tout[i] = d * a5;                  // rowsum of Ahat
    } else {
        o0.x = d * a0; o0.y = d * a1; o0.z = d * a2; o0.w = d * a3;
        o1.x = d * a4;
        o1.y = 0.0f;
    }
    o1.z = 0.0f; o1.w = 0.0f;
    ((float4*)(outf + i * 8))[0] = o0;
    ((float4*)(outf + i * 8))[1] = o1;
}

// Fold weights: Wc = W1 @ W2 (5x64), bc = b1 @ W2 (64).
__global__ void k_fold(const float* __restrict__ W1, const float* __restrict__ b1,
                       const float* __restrict__ W2, float* __restrict__ Wc,
                       float* __restrict__ bc) {
    int j = threadIdx.x;
    if (j < IN_C * OUT_C) {
        int k = j / OUT_C, c = j % OUT_C;
        float acc = 0.0f;
        for (int m = 0; m < HID_C; ++m)
            acc += W1[k * HID_C + m] * W2[m * OUT_C + c];
        Wc[j] = acc;
    } else if (j < IN_C * OUT_C + OUT_C) {
        int c = j - IN_C * OUT_C;
        float acc = 0.0f;
        for (int m = 0; m < HID_C; ++m)
            acc += b1[m] * W2[m * OUT_C + c];
        bc[c] = acc;
    }
}

// out[i, 4q..4q+3] = sum_k agg2[i*8+k]*Wc[k,:] + t[i]*bc + b2  (float4 lanes)
__global__ void k_out(const float* __restrict__ agg2, const float* __restrict__ t,
                      const float* __restrict__ Wc, const float* __restrict__ bc,
                      const float* __restrict__ b2, float* __restrict__ out, int n) {
    int idx = blockIdx.x * blockDim.x + threadIdx.x;
    int i = idx >> 4, q = idx & 15;
    if (i >= n) return;
    const float* a = agg2 + i * 8;
    float ti = t[i];
    float4 acc = ((const float4*)b2)[q];
    float4 bq  = ((const float4*)bc)[q];
    acc.x += ti * bq.x; acc.y += ti * bq.y; acc.z += ti * bq.z; acc.w += ti * bq.w;
    #pragma unroll
    for (int k = 0; k < IN_C; ++k) {
        float ak = a[k];
        float4 wk = ((const float4*)(Wc + k * OUT_C))[q];
        acc.x += ak * wk.x; acc.y += ak * wk.y; acc.z += ak * wk.z; acc.w += ak * wk.w;
    }
    ((float4*)out)[idx] = acc;
}

extern "C" void kernel_launch(void* const* d_in, const int* in_sizes, int n_in,
                              void* d_out, int out_size, void* d_ws, size_t ws_size,
                              hipStream_t stream) {
    const float* x   = (const float*)d_in[0];
    const int*   ei  = (const int*)d_in[1];
    const float* W1  = (const float*)d_in[2];
    const float* b1  = (const float*)d_in[3];
    const float* W2  = (const float*)d_in[4];
    const float* b2  = (const float*)d_in[5];
    float* out = (float*)d_out;

    const int n = in_sizes[0] / IN_C;       // 100000
    const int e = in_sizes[1] / 2;          // 3200000
    const int* src = ei;
    const int* dst = ei + e;
    const int NB = (n + KB - 1) / KB;       // 391
    const int np = (n + 7) & ~7;
    const int ep = (e + 7) & ~7;
    const int NS = NB * S;                  // 1564 slice blocks

    // Workspace layout (4B elements; every segment size multiple of 8)
    int*   gtot    = (int*)d_ws;            // 512
    int*   gbase   = gtot + 512;            // 520
    int*   gcursor = gbase + 520;           // 512 + pad 8 -> 1552 total
    int*   binned  = (int*)d_ws + 1552;     // ep
    int*   ipart   = binned + ep;           // NS*KB      (1564*256)
    float* part    = (float*)(ipart + NS * KB);  // NS*KB*6 (9.6 MB)
    float* xs      = part + (size_t)NS * KB * 6; // 8*np   (reused as agg2)
    float* p1      = xs + 8 * np;           // 8*np
    float* t       = p1 + 8 * np;           // np
    float* Wc      = t + np;                // 320
    float* bc      = Wc + IN_C * OUT_C;     // 64
    float* agg2    = xs;                    // alias: xs dead after pass 1

    const int gN = (n + 255) / 256;
    const int gO = (n * 16 + 255) / 256;
    const int gB = (e + TILE - 1) / TILE;   // 782

    k_zero512<<<1, 512, 0, stream>>>(gtot);
    k_count  <<<512, 256, 0, stream>>>(dst, gtot, e);
    k_scan   <<<1, 512, 0, stream>>>(gtot, gbase, gcursor, e);
    k_bin    <<<gB, BTH, 0, stream>>>(src, dst, gcursor, binned, e);
    k_degs   <<<NS, BTH, 0, stream>>>(binned, gbase, ipart);
    k_prep   <<<gN, 256, 0, stream>>>(x, ipart, xs, n);
    k_fold   <<<1, 384, 0, stream>>>(W1, b1, W2, Wc, bc);
    k_aggs<0><<<NS, BTH, 0, stream>>>(binned, gbase, xs, part);
    k_red<0> <<<gN, 256, 0, stream>>>(part, xs, p1, t, n);
    k_aggs<1><<<NS, BTH, 0, stream>>>(binned, gbase, p1, part);
    k_red<1> <<<gN, 256, 0, stream>>>(part, p1, agg2, t, n);
    k_out    <<<gO, 256, 0, stream>>>(agg2, t, Wc, bc, b2, out, n);
}